// Round 6
// baseline (118.844 us; speedup 1.0000x reference)
//
#include <hip/hip_runtime.h>
#include <stdint.h>

#define T 128              // NUM_STEPS
#define STEPF (1.0f/127.0f)
#define NCOPY 16           // parallel global histogram copies
#define WSSTRIDE 258       // 256 bins + pad, per copy

// ws layout (floats):
//   copy c at [c*WSSTRIDE .. +255]: [0..127] class-0 (neg), [128..255] class-1 (pos)
//   ws[NCOPY*WSSTRIDE]     (uint): count of label==1
//   ws[NCOPY*WSSTRIDE + 1] (uint): blocks-done counter
// All cross-block ws traffic is device-scope atomics (coherent at IC, past XCD L2),
// so no __threadfence is needed; per-wave s_waitcnt vmcnt(0) orders completion.

#define GLOAD(gp, lp) __builtin_amdgcn_global_load_lds(                        \
    (const __attribute__((address_space(1))) void*)(gp),                       \
    (__attribute__((address_space(3))) void*)(lp), 16, 0, 0)

#define AGLOADF(p) __hip_atomic_load((p), __ATOMIC_RELAXED, __HIP_MEMORY_SCOPE_AGENT)

__global__ __launch_bounds__(256) void sim_hist_kernel(
    const float* __restrict__ A, const float* __restrict__ B,
    const int* __restrict__ label, float* __restrict__ ws,
    float* __restrict__ out, int n, int nblocks) {
  // per wave w: 16 A-rows (swizzled) at tile[w*4096], 16 B-rows at tile[w*4096+2048]
  __shared__ __align__(16) float tile[16384];   // 64 KB
  __shared__ float hloc[2 * T];
  __shared__ unsigned int ccnt;
  __shared__ bool amLast;
  const int tid = threadIdx.x;
  hloc[tid] = 0.0f;                  // 256 threads cover 2*T exactly
  if (tid == 0) ccnt = 0u;
  __syncthreads();                   // hist init visible before any wave's atomics

  const int w      = tid >> 6;       // wave id (0..3)
  const int lam    = tid & 63;
  const int lhalf  = lam >> 5;       // which of 2 rows this lane's 16B chunk covers
  const int c32    = lam & 31;       // 16B-chunk index within a 512B row
  const int g      = tid >> 2;       // group (0..63) -> row blk*64+g
  const int gl     = g & 15;         // group within wave
  const int l      = tid & 3;        // lane within group
  const size_t rowbase = (size_t)blockIdx.x * 64 + w * 16;

  const int lv = label[blockIdx.x * 64 + g];   // early, overlaps staging

  // ---- stage: 16 fire-and-forget 1KB global_load_lds per wave ----
  // LDS row r holds global 16B-chunks c ^ ((r&7)<<2): XOR acts on 64B-line index,
  // global side stays coalesced, ds_read side conflict-minimal (both-sides swizzle).
#pragma unroll
  for (int i = 0; i < 8; ++i) {      // A rows 2i, 2i+1
    const int r  = 2 * i + lhalf;
    const int cg = c32 ^ ((r & 7) << 2);
    GLOAD(A + (rowbase + r) * 128 + cg * 4, &tile[w * 4096 + i * 256]);
  }
#pragma unroll
  for (int i = 0; i < 8; ++i) {      // B rows 2i, 2i+1
    const int r  = 2 * i + lhalf;
    const int cg = c32 ^ ((r & 7) << 2);
    GLOAD(B + (rowbase + r) * 128 + cg * 4, &tile[w * 4096 + 2048 + i * 256]);
  }
  asm volatile("s_waitcnt vmcnt(0)" ::: "memory");   // wave-private staging
  __builtin_amdgcn_sched_barrier(0);

  // ---- compute: group reads its row from LDS with the same XOR swizzle ----
  const float* At = &tile[w * 4096 + gl * 128];
  const float* Bt = &tile[w * 4096 + 2048 + gl * 128];
  const int sw = (gl & 7) << 2;
  float ab = 0.f, aa = 0.f, bb = 0.f;
#pragma unroll
  for (int k = 0; k < 8; ++k) {
    const int c = (l + 4 * k) ^ sw;
    const float4 va = *(const float4*)&At[c * 4];
    const float4 vb = *(const float4*)&Bt[c * 4];
    ab = fmaf(va.x, vb.x, fmaf(va.y, vb.y, fmaf(va.z, vb.z, fmaf(va.w, vb.w, ab))));
    aa = fmaf(va.x, va.x, fmaf(va.y, va.y, fmaf(va.z, va.z, fmaf(va.w, va.w, aa))));
    bb = fmaf(vb.x, vb.x, fmaf(vb.y, vb.y, fmaf(vb.z, vb.z, fmaf(vb.w, vb.w, bb))));
  }
  ab += __shfl_xor(ab, 1); ab += __shfl_xor(ab, 2);
  aa += __shfl_xor(aa, 1); aa += __shfl_xor(aa, 2);
  bb += __shfl_xor(bb, 1); bb += __shfl_xor(bb, 2);

  int cnt = 0;
  if (l == 0) {                      // 16 of 64 lanes
    const int lab = (lv == 1) ? 1 : 0;
    cnt = lab;
    const float sim = ab * rsqrtf(aa * bb);
    float s = fminf(fmaxf((sim + 1.0f) * 0.5f, 0.0f), 1.0f);
    const float idxf = floorf(s / STEPF);          // exact reference semantics
    const int idx = (int)idxf;
    const float w0 = (-s + idxf * STEPF + STEPF) / STEPF;
    atomicAdd(&hloc[lab * T + idx], w0);
    if (idx + 1 < T) {
      const float w1 = (s - (idxf + 1.0f) * STEPF + STEPF) / STEPF;
      atomicAdd(&hloc[lab * T + idx + 1], w1);
    }
  }

  // wave-reduce positive count; one LDS atomic per wave
#pragma unroll
  for (int off = 32; off > 0; off >>= 1) cnt += __shfl_xor(cnt, off);
  if (lam == 0 && cnt) atomicAdd(&ccnt, (unsigned int)cnt);
  __syncthreads();

  unsigned int* cntp  = (unsigned int*)(ws + NCOPY * WSSTRIDE);
  unsigned int* donep = cntp + 1;

  // flush block-local histogram (device-scope atomics, coherent at IC)
  float* wsc = ws + (blockIdx.x & (NCOPY - 1)) * WSSTRIDE;
  const float v = hloc[tid];
  if (v != 0.0f) atomicAdd(&wsc[tid], v);
  if (tid == 0 && ccnt) atomicAdd(cntp, ccnt);

  // per-wave completion wait (cheap, wave-local — NOT a device fence)
  asm volatile("s_waitcnt vmcnt(0)" ::: "memory");
  __syncthreads();                   // all 4 waves' atomics are now at the IC

  if (tid == 0) {
    const unsigned int prev = atomicAdd(donep, 1u);
    amLast = (prev == (unsigned int)(nblocks - 1));
  }
  __syncthreads();

  if (amLast && tid < 64) {          // last block computes the loss
    const int lane = tid;
    const int j0 = 2 * lane, j1 = 2 * lane + 1;
    float hp0 = 0.f, hp1 = 0.f, hn0 = 0.f, hn1 = 0.f;
#pragma unroll
    for (int c = 0; c < NCOPY; ++c) {    // agent-scope loads bypass (stale) L2
      const float* wc = ws + c * WSSTRIDE;
      hn0 += AGLOADF(wc + j0);     hn1 += AGLOADF(wc + j1);       // class 0 = neg
      hp0 += AGLOADF(wc + T + j0); hp1 += AGLOADF(wc + T + j1);   // class 1 = pos
    }
    const unsigned int cpos = __hip_atomic_load(cntp, __ATOMIC_RELAXED, __HIP_MEMORY_SCOPE_AGENT);
    const float possz = fmaxf((float)cpos, 1.0f);
    const float negsz = fmaxf((float)(n - (int)cpos), 1.0f);
    hp0 /= possz; hp1 /= possz;
    hn0 /= negsz; hn1 /= negsz;

    const float pair = hp0 + hp1;
    float scan = pair;                   // inclusive scan of pair-sums
#pragma unroll
    for (int off = 1; off < 64; off <<= 1) {
      const float u = __shfl_up(scan, off);
      if (lane >= off) scan += u;
    }
    const float excl = scan - pair;
    float part = (excl + hp0) * hn0 + (excl + hp0 + hp1) * hn1;
#pragma unroll
    for (int off = 32; off > 0; off >>= 1) part += __shfl_xor(part, off);
    if (lane == 0) out[0] = part;
  }
}

extern "C" void kernel_launch(void* const* d_in, const int* in_sizes, int n_in,
                              void* d_out, int out_size, void* d_ws, size_t ws_size,
                              hipStream_t stream) {
  const float* A  = (const float*)d_in[0];
  const float* B  = (const float*)d_in[1];
  const int* lab  = (const int*)d_in[2];
  const int n = in_sizes[2];                 // N = 262144 (divisible by 64)
  float* ws = (float*)d_ws;

  hipMemsetAsync(d_ws, 0, (NCOPY * WSSTRIDE + 2) * sizeof(float), stream);

  const int grid = n >> 6;                   // 64 rows per block -> 4096 blocks
  sim_hist_kernel<<<grid, 256, 0, stream>>>(A, B, lab, ws, (float*)d_out, n, grid);
}

// Round 7
// 52.441 us; speedup vs baseline: 2.2662x; 2.2662x over previous
//
#include <hip/hip_runtime.h>
#include <stdint.h>

#define T 128              // NUM_STEPS
#define STEPF (1.0f/127.0f)
#define NCOPY 8            // parallel global histogram copies
#define WSSTRIDE 258       // 256 bins + 1 count + 1 pad, per copy

// ws layout per copy c (floats, base = c*WSSTRIDE):
//   [0..127] class-0 (neg), [128..255] class-1 (pos), [256] (uint) count(label==1)

// fire-and-forget global->LDS, 16B per lane (64 lanes -> 1KB contiguous LDS)
#define GLOAD(gp, lp) __builtin_amdgcn_global_load_lds(                        \
    (const __attribute__((address_space(1))) void*)(gp),                       \
    (__attribute__((address_space(3))) void*)(lp), 16, 0, 0)

__global__ __launch_bounds__(256) void sim_hist_kernel(
    const float* __restrict__ A, const float* __restrict__ B,
    const int* __restrict__ label, float* __restrict__ ws, int n) {
  // per wave w: 16 A-rows (swizzled) at tile[w*2048]; B goes direct to VGPRs
  __shared__ __align__(16) float tile[8192];    // 32 KB -> 4 blocks/CU
  __shared__ float hloc[2 * T];
  __shared__ unsigned int ccnt;
  const int tid = threadIdx.x;
  hloc[tid] = 0.0f;                  // 256 threads cover 2*T exactly
  if (tid == 0) ccnt = 0u;
  __syncthreads();                   // hist init visible before any wave's atomics

  const int w      = tid >> 6;       // wave id (0..3)
  const int lam    = tid & 63;
  const int lhalf  = lam >> 5;       // which of the 2 rows this lane's chunk covers
  const int c32    = lam & 31;       // 16B-chunk index within a 512B row
  const int g      = tid >> 2;       // group (0..63) -> row blk*64+g
  const int gl     = g & 15;         // group within wave
  const int l      = tid & 3;        // lane within group
  const size_t rowbase = (size_t)blockIdx.x * 64 + w * 16;
  const size_t myrow   = (size_t)blockIdx.x * 64 + g;

  const int lv = label[myrow];       // early, overlaps staging

  // ---- stage A: 8 fire-and-forget 1KB global_load_lds per wave (zero VGPR) ----
  // LDS row r holds global 16B-chunks c ^ ((r&7)<<2): XOR on 64B-line index keeps
  // the global side coalesced and the ds_read side conflict-minimal.
#pragma unroll
  for (int i = 0; i < 8; ++i) {      // A rows 2i, 2i+1
    const int r  = 2 * i + lhalf;
    const int cg = c32 ^ ((r & 7) << 2);
    GLOAD(A + (rowbase + r) * 128 + cg * 4, &tile[w * 2048 + i * 256]);
  }

  // ---- B direct to VGPRs: 8 independent float4 per lane, all issued up front ----
  const float4* __restrict__ b4 = (const float4*)B + myrow * 32 + l;
  float4 vb[8];
#pragma unroll
  for (int k = 0; k < 8; ++k) vb[k] = b4[k * 4];

  float bb = 0.f;
#pragma unroll
  for (int k = 0; k < 8; ++k)        // B self-product while A staging drains
    bb = fmaf(vb[k].x, vb[k].x, fmaf(vb[k].y, vb[k].y, fmaf(vb[k].z, vb[k].z, fmaf(vb[k].w, vb[k].w, bb))));

  asm volatile("s_waitcnt vmcnt(0)" ::: "memory");   // A staged (wave-private)
  __builtin_amdgcn_sched_barrier(0);

  // ---- compute: group reads its A-row from LDS with the same XOR swizzle ----
  const float* At = &tile[w * 2048 + gl * 128];
  const int sw = (gl & 7) << 2;
  float ab = 0.f, aa = 0.f;
#pragma unroll
  for (int k = 0; k < 8; ++k) {
    const int c = (l + 4 * k) ^ sw;            // chunk holding A elements for (l,k)
    const float4 va = *(const float4*)&At[c * 4];
    const int kk = (c ^ sw) >> 2;              // = k; vb indexed by original chunk
    const float4 vB = vb[kk];
    ab = fmaf(va.x, vB.x, fmaf(va.y, vB.y, fmaf(va.z, vB.z, fmaf(va.w, vB.w, ab))));
    aa = fmaf(va.x, va.x, fmaf(va.y, va.y, fmaf(va.z, va.z, fmaf(va.w, va.w, aa))));
  }
  ab += __shfl_xor(ab, 1); ab += __shfl_xor(ab, 2);
  aa += __shfl_xor(aa, 1); aa += __shfl_xor(aa, 2);
  bb += __shfl_xor(bb, 1); bb += __shfl_xor(bb, 2);

  int cnt = 0;
  if (l == 0) {                      // 16 of 64 lanes
    const int lab = (lv == 1) ? 1 : 0;
    cnt = lab;
    const float sim = ab * rsqrtf(aa * bb);
    float s = fminf(fmaxf((sim + 1.0f) * 0.5f, 0.0f), 1.0f);
    const float idxf = floorf(s / STEPF);      // exact reference semantics
    const int idx = (int)idxf;
    const float w0 = (-s + idxf * STEPF + STEPF) / STEPF;
    atomicAdd(&hloc[lab * T + idx], w0);
    if (idx + 1 < T) {
      const float w1 = (s - (idxf + 1.0f) * STEPF + STEPF) / STEPF;
      atomicAdd(&hloc[lab * T + idx + 1], w1);
    }
  }

  // wave-reduce positive count; one LDS atomic per wave
#pragma unroll
  for (int off = 32; off > 0; off >>= 1) cnt += __shfl_xor(cnt, off);
  if (lam == 0 && cnt) atomicAdd(&ccnt, (unsigned int)cnt);
  __syncthreads();

  // fire-and-forget flush — NO completion wait after this (round-6 lesson)
  float* wsc = ws + (blockIdx.x & (NCOPY - 1)) * WSSTRIDE;
  const float v = hloc[tid];
  if (v != 0.0f) atomicAdd(&wsc[tid], v);
  if (tid == 0 && ccnt) atomicAdd((unsigned int*)(wsc + 2 * T), ccnt);
}

// single-wave parallel finalize: 2 bins per lane, shuffle prefix-scan
__global__ void finalize_kernel(const float* __restrict__ ws, float* __restrict__ out, int n) {
  const int lane = threadIdx.x & 63;
  unsigned int cpos = 0;
  float hp0 = 0.f, hp1 = 0.f, hn0 = 0.f, hn1 = 0.f;
  const int j0 = 2 * lane, j1 = 2 * lane + 1;
#pragma unroll
  for (int c = 0; c < NCOPY; ++c) {
    const float* wsc = ws + c * WSSTRIDE;
    hn0 += wsc[j0];       hn1 += wsc[j1];      // class 0 = neg
    hp0 += wsc[T + j0];   hp1 += wsc[T + j1];  // class 1 = pos
    cpos += ((const unsigned int*)(wsc + 2 * T))[0];
  }
  const float possz = fmaxf((float)cpos, 1.0f);
  const float negsz = fmaxf((float)(n - (int)cpos), 1.0f);
  hp0 /= possz; hp1 /= possz;
  hn0 /= negsz; hn1 /= negsz;

  const float pair = hp0 + hp1;
  float scan = pair;                           // inclusive scan of pair-sums
#pragma unroll
  for (int off = 1; off < 64; off <<= 1) {
    const float u = __shfl_up(scan, off);
    if (lane >= off) scan += u;
  }
  const float excl = scan - pair;
  float part = (excl + hp0) * hn0 + (excl + hp0 + hp1) * hn1;
#pragma unroll
  for (int off = 32; off > 0; off >>= 1) part += __shfl_xor(part, off);
  if (lane == 0) out[0] = part;
}

extern "C" void kernel_launch(void* const* d_in, const int* in_sizes, int n_in,
                              void* d_out, int out_size, void* d_ws, size_t ws_size,
                              hipStream_t stream) {
  const float* A  = (const float*)d_in[0];
  const float* B  = (const float*)d_in[1];
  const int* lab  = (const int*)d_in[2];
  const int n = in_sizes[2];                 // N = 262144 (divisible by 64)
  float* ws = (float*)d_ws;

  hipMemsetAsync(d_ws, 0, NCOPY * WSSTRIDE * sizeof(float), stream);

  const int grid = n >> 6;                   // 64 rows per block -> 4096 blocks
  sim_hist_kernel<<<grid, 256, 0, stream>>>(A, B, lab, ws, n);
  finalize_kernel<<<1, 64, 0, stream>>>(ws, (float*)d_out, n);
}